// Round 4
// baseline (124.677 us; speedup 1.0000x reference)
//
#include <hip/hip_runtime.h>
#include <math.h>

#define N 4096
#define D 128
#define TS 64                      // output tile per 256-thread block
#define NT (N / TS)                // 64 tile rows
#define NBLK (NT * (NT + 1) / 2)   // 2080 lower-triangle tile pairs
#define HBLK (NBLK / 2)            // 1040 blocks, 2 tiles each (pipelined)
#define NG (N / 16)                // 256 row groups of 16

typedef __attribute__((ext_vector_type(8))) short short8;  // 8 x bf16
typedef __attribute__((ext_vector_type(4))) float f32x4;

union frag_u { short8 v; unsigned int u[4]; };

__device__ __forceinline__ unsigned int pack_bf16x2(float a, float b) {
    unsigned int ua = __float_as_uint(a), ub = __float_as_uint(b);
    ua = (ua + 0x7FFFu + ((ua >> 16) & 1u)) >> 16;
    ub = (ub + 0x7FFFu + ((ub >> 16) & 1u)) >> 16;
    return ua | (ub << 16);
}

// Kernel 1: repack O into MFMA-fragment order + compute s[i]=sqrt(1+||o_i||^2).
__global__ __launch_bounds__(256)
void prep_kernel(const float* __restrict__ O,
                 short8* __restrict__ Ofrag,
                 float* __restrict__ s) {
    __shared__ float psum[16][17];
    const int g    = blockIdx.x;          // 16-row group
    const int tid  = threadIdx.x;
    const int kk   = tid >> 6;            // 0..3 (wave = K-chunk)
    const int lane = tid & 63;
    const int r16  = lane & 15;
    const int qd   = lane >> 4;           // 0..3
    const float* src = O + (size_t)(g * 16 + r16) * D + kk * 32 + qd * 8;
    const float4 v0 = *(const float4*)(src);
    const float4 v1 = *(const float4*)(src + 4);
    frag_u f;
    f.u[0] = pack_bf16x2(v0.x, v0.y);
    f.u[1] = pack_bf16x2(v0.z, v0.w);
    f.u[2] = pack_bf16x2(v1.x, v1.y);
    f.u[3] = pack_bf16x2(v1.z, v1.w);
    Ofrag[(g * 4 + kk) * 64 + lane] = f.v;
    psum[kk * 4 + qd][r16] = v0.x * v0.x + v0.y * v0.y + v0.z * v0.z + v0.w * v0.w
                           + v1.x * v1.x + v1.y * v1.y + v1.z * v1.z + v1.w * v1.w;
    __syncthreads();
    if (tid < 16) {
        float acc = 1.0f;
        #pragma unroll
        for (int x = 0; x < 16; x++) acc += psum[x][tid];
        s[g * 16 + tid] = sqrtf(acc);
    }
}

__device__ __forceinline__ float acosh_dist(float B) {
    // clamp branch |B-1|<1e-6 -> 0 (inert here: B >= ~100 for this data)
    if (fabsf(B - 1.0f) < 1e-6f) return 0.0f;
    const float Bc = fmaxf(B, 1.0f);
    return __log2f(Bc + sqrtf(fmaf(Bc, Bc, -1.0f))) * 0.6931471805599453f;
}

// Async 16B global->LDS (no VGPR round-trip). LDS dest is wave-uniform base;
// HW adds lane*16 bytes.
__device__ __forceinline__ void gload_lds16(const float* g, float* l) {
    __builtin_amdgcn_global_load_lds(
        (const __attribute__((address_space(1))) unsigned int*)g,
        (__attribute__((address_space(3))) unsigned int*)l,
        16, 0, 0);
}

__device__ __forceinline__ void tile_ij(int t, int& ti_, int& tj_) {
    int x = (int)((sqrtf(8.0f * (float)t + 1.0f) - 1.0f) * 0.5f);
    while ((x + 1) * (x + 2) / 2 <= t) x++;
    while (x * (x + 1) / 2 > t) x--;
    ti_ = x;
    tj_ = t - x * (x + 1) / 2;
}

// Epilogue for one tile. C/D layout: col = l16 (+n*16), row = quad*4 + reg.
__device__ __forceinline__ float tile_epilogue(const f32x4 acc[4],
                                               const float si[4], const float sj[4],
                                               const float (*Tt)[TS],
                                               int r0, int l16, int ib0, int jb,
                                               int diag) {
    float lsum = 0.0f;
    if (!diag) {
        #pragma unroll
        for (int r = 0; r < 4; r++)
            #pragma unroll
            for (int n = 0; n < 4; n++) {
                const float B = fmaf(si[r], sj[n], -acc[n][r]);
                lsum += fabsf(acosh_dist(B) - Tt[r0 + r][n * 16 + l16]);
            }
    } else {
        #pragma unroll
        for (int r = 0; r < 4; r++) {
            const int i = ib0 + r0 + r;
            #pragma unroll
            for (int n = 0; n < 4; n++) {
                const int j = jb + n * 16 + l16;
                if (j < i)
                    lsum += fabsf(acosh_dist(fmaf(si[r], sj[n], -acc[n][r]))
                                  - Tt[r0 + r][n * 16 + l16]);
            }
        }
    }
    return lsum;
}

// Kernel 2: 1040 blocks, 2 tiles each, software-pipelined:
//   DMA A->T[0]  |  A-frags  |  [fence] DMA B->T[1] (newest 16 VMEM) [fence]
//   MFMA A  |  vmcnt(16) + raw s_barrier (B DMAs stay in flight!)
//   epilogue A (T[0])  overlapped with  B-frag issue
//   MFMA B  |  vmcnt(0) + raw s_barrier  |  epilogue B (T[1])
// Raw s_barrier + counted vmcnt avoids __syncthreads' compiler-emitted
// vmcnt(0) drain that would kill the pipeline (m97 barrier-drain trap).
// Per-tile sums / reduce order / partials indexing unchanged -> bit-identical.
__global__ __launch_bounds__(256, 4)
void tile_loss_kernel(const short8* __restrict__ Fr,
                      const float* __restrict__ s,
                      const float* __restrict__ tgt,
                      float* __restrict__ partials) {
    __shared__ float T[2][TS][TS];   // 32 KB
    __shared__ float wsum[2][4];

    const int tid  = threadIdx.x;
    const int wave = tid >> 6;
    const int lane = tid & 63;
    const int quad = lane >> 4;
    const int l16  = lane & 15;
    const int r0   = wave * 16 + quad * 4;

    const int tA = blockIdx.x;
    const int tB = tA + HBLK;
    int tiA, tjA, tiB, tjB;
    tile_ij(tA, tiA, tjA);
    tile_ij(tB, tiB, tjB);
    const int ibA = tiA * TS, jbA = tjA * TS;
    const int ibB = tiB * TS, jbB = tjB * TS;

    // ---- 1) DMA tile-A tgt -> T[0] (oldest VMEM ops in flight).
    {
        const float* g = tgt + (size_t)(ibA + wave * 16 + quad) * N + jbA + l16 * 4;
        #pragma unroll
        for (int q = 0; q < 4; q++)
            gload_lds16(g + (size_t)q * 4 * N, &T[0][wave * 16 + q * 4][0]);
    }

    // ---- 2) A-frags (a: 4, b: 16; 1 KB contiguous bursts).
    short8 a[4], b[4][4];
    #pragma unroll
    for (int k = 0; k < 4; k++)
        a[k] = Fr[((tiA * 4 + wave) * 4 + k) * 64 + lane];
    #pragma unroll
    for (int n = 0; n < 4; n++)
        #pragma unroll
        for (int k = 0; k < 4; k++)
            b[n][k] = Fr[((tjA * 4 + n) * 4 + k) * 64 + lane];

    // ---- 3) DMA tile-B tgt -> T[1], pinned as the NEWEST 16 VMEM ops so
    // vmcnt(16) below provably waits for everything older (T[0] + frags).
    __builtin_amdgcn_sched_barrier(0);
    {
        const float* g = tgt + (size_t)(ibB + wave * 16 + quad) * N + jbB + l16 * 4;
        #pragma unroll
        for (int q = 0; q < 4; q++)
            gload_lds16(g + (size_t)q * 4 * N, &T[1][wave * 16 + q * 4][0]);
    }
    __builtin_amdgcn_sched_barrier(0);

    // ---- 4) MFMA tile A (compiler waits on frag regs only).
    f32x4 acc[4] = {};
    #pragma unroll
    for (int k = 0; k < 4; k++)
        #pragma unroll
        for (int n = 0; n < 4; n++)
            acc[n] = __builtin_amdgcn_mfma_f32_16x16x32_bf16(a[k], b[n][k], acc[n], 0, 0, 0);

    // ---- 5) T[0] ready when only B's 16 DMAs may remain outstanding.
    asm volatile("s_waitcnt vmcnt(16)" ::: "memory");
    __builtin_amdgcn_s_barrier();

    // ---- 6) Issue B-frags + s-values now: latency hides under epilogue A.
    // (A-frags in a/b are dead after MFMA A -> registers reuse.)
    #pragma unroll
    for (int k = 0; k < 4; k++)
        a[k] = Fr[((tiB * 4 + wave) * 4 + k) * 64 + lane];
    #pragma unroll
    for (int n = 0; n < 4; n++)
        #pragma unroll
        for (int k = 0; k < 4; k++)
            b[n][k] = Fr[((tjB * 4 + n) * 4 + k) * 64 + lane];
    float siA[4], sjA[4], siB[4], sjB[4];
    #pragma unroll
    for (int r = 0; r < 4; r++) siA[r] = s[ibA + r0 + r];
    #pragma unroll
    for (int n = 0; n < 4; n++) sjA[n] = s[jbA + n * 16 + l16];
    #pragma unroll
    for (int r = 0; r < 4; r++) siB[r] = s[ibB + r0 + r];
    #pragma unroll
    for (int n = 0; n < 4; n++) sjB[n] = s[jbB + n * 16 + l16];

    // ---- 7) Epilogue A.
    float lsum = tile_epilogue(acc, siA, sjA, T[0], r0, l16, ibA, jbA, tiA == tjA);
    #pragma unroll
    for (int off = 32; off > 0; off >>= 1)
        lsum += __shfl_down(lsum, off, 64);
    if (lane == 0) wsum[0][wave] = lsum;
    asm volatile("s_waitcnt lgkmcnt(0)" ::: "memory");
    __builtin_amdgcn_s_barrier();
    if (tid == 0)
        partials[tA] = wsum[0][0] + wsum[0][1] + wsum[0][2] + wsum[0][3];

    // ---- 8) MFMA tile B.
    #pragma unroll
    for (int n = 0; n < 4; n++) acc[n] = (f32x4){0.0f, 0.0f, 0.0f, 0.0f};
    #pragma unroll
    for (int k = 0; k < 4; k++)
        #pragma unroll
        for (int n = 0; n < 4; n++)
            acc[n] = __builtin_amdgcn_mfma_f32_16x16x32_bf16(a[k], b[n][k], acc[n], 0, 0, 0);

    // ---- 9) T[1] ready (DMAs issued at step 3 -- long since complete).
    asm volatile("s_waitcnt vmcnt(0)" ::: "memory");
    __builtin_amdgcn_s_barrier();

    // ---- 10) Epilogue B.
    float lsumB = tile_epilogue(acc, siB, sjB, T[1], r0, l16, ibB, jbB, tiB == tjB);
    #pragma unroll
    for (int off = 32; off > 0; off >>= 1)
        lsumB += __shfl_down(lsumB, off, 64);
    if (lane == 0) wsum[1][wave] = lsumB;
    asm volatile("s_waitcnt lgkmcnt(0)" ::: "memory");
    __builtin_amdgcn_s_barrier();
    if (tid == 0)
        partials[tB] = wsum[1][0] + wsum[1][1] + wsum[1][2] + wsum[1][3];
}

// Kernel 3: reduce the 2080 block partials, scale, write the scalar loss.
__global__ __launch_bounds__(256)
void final_reduce_kernel(const float* __restrict__ partials,
                         float* __restrict__ loss) {
    __shared__ float wsum[4];
    const int tid  = threadIdx.x;
    const int wave = tid >> 6;
    const int lane = tid & 63;
    float acc = 0.0f;
    for (int i = tid; i < NBLK; i += 256) acc += partials[i];
    #pragma unroll
    for (int off = 32; off > 0; off >>= 1)
        acc += __shfl_down(acc, off, 64);
    if (lane == 0) wsum[wave] = acc;
    __syncthreads();
    if (tid == 0) {
        const float tot = wsum[0] + wsum[1] + wsum[2] + wsum[3];
        loss[0] = tot * (1.0f / ((float)N * (float)(N - 1)));
    }
}

extern "C" void kernel_launch(void* const* d_in, const int* in_sizes, int n_in,
                              void* d_out, int out_size, void* d_ws, size_t ws_size,
                              hipStream_t stream) {
    const float* O   = (const float*)d_in[0];   // [4096,128] fp32
    const float* tgt = (const float*)d_in[1];   // [4096,4096] fp32
    float* loss = (float*)d_out;                // scalar

    // ws layout: [0,1MB) frag-ordered bf16 O; [1MB,+16KB) s[]; then partials
    short8* Ofrag = (short8*)d_ws;
    float* s        = (float*)((char*)d_ws + (size_t)N * D * 2);
    float* partials = s + N;

    prep_kernel<<<NG, 256, 0, stream>>>(O, Ofrag, s);
    tile_loss_kernel<<<HBLK, 256, 0, stream>>>(Ofrag, s, tgt, partials);
    final_reduce_kernel<<<1, 256, 0, stream>>>(partials, loss);
}

// Round 5
// 107.306 us; speedup vs baseline: 1.1619x; 1.1619x over previous
//
#include <hip/hip_runtime.h>
#include <math.h>

#define N 4096
#define D 128
#define TS 64                      // output tile per 256-thread block
#define NT (N / TS)                // 64 tile rows
#define NBLK (NT * (NT + 1) / 2)   // 2080 lower-triangle tile pairs
#define HBLK (NBLK / 2)            // 1040 blocks, 2 tiles each (pipelined)
#define NG (N / 16)                // 256 row groups of 16

typedef __attribute__((ext_vector_type(8))) short short8;  // 8 x bf16
typedef __attribute__((ext_vector_type(4))) float f32x4;

union frag_u { short8 v; unsigned int u[4]; };

__device__ __forceinline__ unsigned int pack_bf16x2(float a, float b) {
    unsigned int ua = __float_as_uint(a), ub = __float_as_uint(b);
    ua = (ua + 0x7FFFu + ((ua >> 16) & 1u)) >> 16;
    ub = (ub + 0x7FFFu + ((ub >> 16) & 1u)) >> 16;
    return ua | (ub << 16);
}

// Kernel 1: repack O into MFMA-fragment order + compute s[i]=sqrt(1+||o_i||^2).
__global__ __launch_bounds__(256)
void prep_kernel(const float* __restrict__ O,
                 short8* __restrict__ Ofrag,
                 float* __restrict__ s) {
    __shared__ float psum[16][17];
    const int g    = blockIdx.x;          // 16-row group
    const int tid  = threadIdx.x;
    const int kk   = tid >> 6;            // 0..3 (wave = K-chunk)
    const int lane = tid & 63;
    const int r16  = lane & 15;
    const int qd   = lane >> 4;           // 0..3
    const float* src = O + (size_t)(g * 16 + r16) * D + kk * 32 + qd * 8;
    const float4 v0 = *(const float4*)(src);
    const float4 v1 = *(const float4*)(src + 4);
    frag_u f;
    f.u[0] = pack_bf16x2(v0.x, v0.y);
    f.u[1] = pack_bf16x2(v0.z, v0.w);
    f.u[2] = pack_bf16x2(v1.x, v1.y);
    f.u[3] = pack_bf16x2(v1.z, v1.w);
    Ofrag[(g * 4 + kk) * 64 + lane] = f.v;
    psum[kk * 4 + qd][r16] = v0.x * v0.x + v0.y * v0.y + v0.z * v0.z + v0.w * v0.w
                           + v1.x * v1.x + v1.y * v1.y + v1.z * v1.z + v1.w * v1.w;
    __syncthreads();
    if (tid < 16) {
        float acc = 1.0f;
        #pragma unroll
        for (int x = 0; x < 16; x++) acc += psum[x][tid];
        s[g * 16 + tid] = sqrtf(acc);
    }
}

__device__ __forceinline__ float acosh_dist(float B) {
    // clamp branch |B-1|<1e-6 -> 0 (inert here: B >= ~100 for this data)
    if (fabsf(B - 1.0f) < 1e-6f) return 0.0f;
    const float Bc = fmaxf(B, 1.0f);
    return __log2f(Bc + sqrtf(fmaf(Bc, Bc, -1.0f))) * 0.6931471805599453f;
}

// Async 16B global->LDS (no VGPR round-trip). LDS dest is wave-uniform base;
// HW adds lane*16 bytes.
__device__ __forceinline__ void gload_lds16(const float* g, float* l) {
    __builtin_amdgcn_global_load_lds(
        (const __attribute__((address_space(1))) unsigned int*)g,
        (__attribute__((address_space(3))) unsigned int*)l,
        16, 0, 0);
}

__device__ __forceinline__ void tile_ij(int t, int& ti_, int& tj_) {
    int x = (int)((sqrtf(8.0f * (float)t + 1.0f) - 1.0f) * 0.5f);
    while ((x + 1) * (x + 2) / 2 <= t) x++;
    while (x * (x + 1) / 2 > t) x--;
    ti_ = x;
    tj_ = t - x * (x + 1) / 2;
}

// Epilogue for one tile. C/D layout: col = l16 (+n*16), row = quad*4 + reg.
// NOTE: wave w touches only T rows [16w,16w+16) -- the exact rows its own
// DMAs wrote -> per-wave vmcnt suffices, NO barrier needed.
__device__ __forceinline__ float tile_epilogue(const f32x4 acc[4],
                                               const float si[4], const float sj[4],
                                               const float (*Tt)[TS],
                                               int r0, int l16, int ib0, int jb,
                                               int diag) {
    float lsum = 0.0f;
    if (!diag) {
        #pragma unroll
        for (int r = 0; r < 4; r++)
            #pragma unroll
            for (int n = 0; n < 4; n++) {
                const float B = fmaf(si[r], sj[n], -acc[n][r]);
                lsum += fabsf(acosh_dist(B) - Tt[r0 + r][n * 16 + l16]);
            }
    } else {
        #pragma unroll
        for (int r = 0; r < 4; r++) {
            const int i = ib0 + r0 + r;
            #pragma unroll
            for (int n = 0; n < 4; n++) {
                const int j = jb + n * 16 + l16;
                if (j < i)
                    lsum += fabsf(acosh_dist(fmaf(si[r], sj[n], -acc[n][r]))
                                  - Tt[r0 + r][n * 16 + l16]);
            }
        }
    }
    return lsum;
}

// Kernel 2: 1040 blocks x 2 tiles, BARRIER-FREE (waves fully decoupled):
//   DMA A->T[0] | frags A + sA | [fence] DMA B->T[1] (newest 4 VMEM/wave) [fence]
//   MFMA A (frag waits imply DMA-A done: in-order vmcnt, DMA-A is older)
//   vmcnt(4): everything but B's 4 DMAs complete -> epilogue A from T[0]
//   wave-partial -> global wpart[tA*4+w] (no LDS reduce, no barrier)
//   frags B + sB | MFMA B | vmcnt(0) | epilogue B -> wpart[tB*4+w]
// Only ONE tile of frags is ever live (~116 VGPR < 128 cap) -- the R2/R4
// spill trap (2x frags resident) is structurally excluded; tile-B prefetch
// is DMA-only (zero registers).
__global__ __launch_bounds__(256, 4)
void tile_loss_kernel(const short8* __restrict__ Fr,
                      const float* __restrict__ s,
                      const float* __restrict__ tgt,
                      float* __restrict__ wpart) {
    __shared__ float T[2][TS][TS];   // 32 KB

    const int tid  = threadIdx.x;
    const int wave = tid >> 6;
    const int lane = tid & 63;
    const int quad = lane >> 4;
    const int l16  = lane & 15;
    const int r0   = wave * 16 + quad * 4;

    const int tA = blockIdx.x;
    const int tB = tA + HBLK;
    int tiA, tjA, tiB, tjB;
    tile_ij(tA, tiA, tjA);
    tile_ij(tB, tiB, tjB);
    const int ibA = tiA * TS, jbA = tjA * TS;
    const int ibB = tiB * TS, jbB = tjB * TS;

    // ---- 1) DMA tile-A tgt -> T[0] (oldest VMEM ops of this wave).
    {
        const float* g = tgt + (size_t)(ibA + wave * 16 + quad) * N + jbA + l16 * 4;
        #pragma unroll
        for (int q = 0; q < 4; q++)
            gload_lds16(g + (size_t)q * 4 * N, &T[0][wave * 16 + q * 4][0]);
    }
    __builtin_amdgcn_sched_barrier(0);

    // ---- 2) A-frags (a: 4, b: 16; 1 KB contiguous bursts) + s-values A.
    short8 a[4], b[4][4];
    #pragma unroll
    for (int k = 0; k < 4; k++)
        a[k] = Fr[((tiA * 4 + wave) * 4 + k) * 64 + lane];
    #pragma unroll
    for (int n = 0; n < 4; n++)
        #pragma unroll
        for (int k = 0; k < 4; k++)
            b[n][k] = Fr[((tjA * 4 + n) * 4 + k) * 64 + lane];
    float siA[4], sjA[4];
    #pragma unroll
    for (int r = 0; r < 4; r++) siA[r] = s[ibA + r0 + r];
    #pragma unroll
    for (int n = 0; n < 4; n++) sjA[n] = s[jbA + n * 16 + l16];

    // ---- 3) DMA tile-B tgt -> T[1], pinned as the NEWEST 4 VMEM ops/wave
    // so vmcnt(4) below provably waits for everything older.
    __builtin_amdgcn_sched_barrier(0);
    {
        const float* g = tgt + (size_t)(ibB + wave * 16 + quad) * N + jbB + l16 * 4;
        #pragma unroll
        for (int q = 0; q < 4; q++)
            gload_lds16(g + (size_t)q * 4 * N, &T[1][wave * 16 + q * 4][0]);
    }
    __builtin_amdgcn_sched_barrier(0);

    // ---- 4) MFMA tile A (compiler waits on frag regs only).
    f32x4 acc[4] = {};
    #pragma unroll
    for (int k = 0; k < 4; k++)
        #pragma unroll
        for (int n = 0; n < 4; n++)
            acc[n] = __builtin_amdgcn_mfma_f32_16x16x32_bf16(a[k], b[n][k], acc[n], 0, 0, 0);

    // ---- 5) T[0] rows of THIS wave ready once only B's 4 DMAs remain.
    asm volatile("s_waitcnt vmcnt(4)" ::: "memory");
    __builtin_amdgcn_sched_barrier(0);

    // ---- 6) Epilogue A; wave-partial straight to global (no LDS, no barrier).
    float lsum = tile_epilogue(acc, siA, sjA, T[0], r0, l16, ibA, jbA, tiA == tjA);
    #pragma unroll
    for (int off = 32; off > 0; off >>= 1)
        lsum += __shfl_down(lsum, off, 64);
    if (lane == 0) wpart[tA * 4 + wave] = lsum;

    // ---- 7) B-frags + s-values B (registers of tile A now dead -> reuse).
    #pragma unroll
    for (int k = 0; k < 4; k++)
        a[k] = Fr[((tiB * 4 + wave) * 4 + k) * 64 + lane];
    #pragma unroll
    for (int n = 0; n < 4; n++)
        #pragma unroll
        for (int k = 0; k < 4; k++)
            b[n][k] = Fr[((tjB * 4 + n) * 4 + k) * 64 + lane];
    float siB[4], sjB[4];
    #pragma unroll
    for (int r = 0; r < 4; r++) siB[r] = s[ibB + r0 + r];
    #pragma unroll
    for (int n = 0; n < 4; n++) sjB[n] = s[jbB + n * 16 + l16];

    // ---- 8) MFMA tile B.
    #pragma unroll
    for (int n = 0; n < 4; n++) acc[n] = (f32x4){0.0f, 0.0f, 0.0f, 0.0f};
    #pragma unroll
    for (int k = 0; k < 4; k++)
        #pragma unroll
        for (int n = 0; n < 4; n++)
            acc[n] = __builtin_amdgcn_mfma_f32_16x16x32_bf16(a[k], b[n][k], acc[n], 0, 0, 0);

    // ---- 9) All VMEM drained (B DMAs are older than B frags -> already done).
    asm volatile("s_waitcnt vmcnt(0)" ::: "memory");
    __builtin_amdgcn_sched_barrier(0);

    // ---- 10) Epilogue B.
    float lsumB = tile_epilogue(acc, siB, sjB, T[1], r0, l16, ibB, jbB, tiB == tjB);
    #pragma unroll
    for (int off = 32; off > 0; off >>= 1)
        lsumB += __shfl_down(lsumB, off, 64);
    if (lane == 0) wpart[tB * 4 + wave] = lsumB;
}

// Kernel 3: reduce 2080x4 wave-partials. Regrouping ((w0+w1)+w2)+w3 per tile
// reproduces the old per-block partial bit-exactly, then the same strided
// accumulation -> bit-identical loss.
__global__ __launch_bounds__(256)
void final_reduce_kernel(const float* __restrict__ wpart,
                         float* __restrict__ loss) {
    __shared__ float wsum[4];
    const int tid  = threadIdx.x;
    const int wave = tid >> 6;
    const int lane = tid & 63;
    float acc = 0.0f;
    for (int i = tid; i < NBLK; i += 256) {
        const float4 wp = ((const float4*)wpart)[i];
        acc += ((wp.x + wp.y) + wp.z) + wp.w;
    }
    #pragma unroll
    for (int off = 32; off > 0; off >>= 1)
        acc += __shfl_down(acc, off, 64);
    if (lane == 0) wsum[wave] = acc;
    __syncthreads();
    if (tid == 0) {
        const float tot = wsum[0] + wsum[1] + wsum[2] + wsum[3];
        loss[0] = tot * (1.0f / ((float)N * (float)(N - 1)));
    }
}

extern "C" void kernel_launch(void* const* d_in, const int* in_sizes, int n_in,
                              void* d_out, int out_size, void* d_ws, size_t ws_size,
                              hipStream_t stream) {
    const float* O   = (const float*)d_in[0];   // [4096,128] fp32
    const float* tgt = (const float*)d_in[1];   // [4096,4096] fp32
    float* loss = (float*)d_out;                // scalar

    // ws layout: [0,1MB) frag-ordered bf16 O; [1MB,+16KB) s[]; then wave partials
    short8* Ofrag = (short8*)d_ws;
    float* s      = (float*)((char*)d_ws + (size_t)N * D * 2);
    float* wpart  = s + N;                      // NBLK*4 floats, 16B-aligned

    prep_kernel<<<NG, 256, 0, stream>>>(O, Ofrag, s);
    tile_loss_kernel<<<HBLK, 256, 0, stream>>>(Ofrag, s, tgt, wpart);
    final_reduce_kernel<<<1, 256, 0, stream>>>(wpart, loss);
}